// Round 1
// baseline (14319.183 us; speedup 1.0000x reference)
//
#include <hip/hip_runtime.h>
#include <hip/hip_bf16.h>
#include <math.h>

// Problem dims (compile-time)
#define B_SZ 2
#define L_SZ 1024
#define BL (B_SZ * L_SZ)          // 2048 tokens
#define D_MODEL 768
#define N_LAYER 6
#define VOCAB 32000
#define D_INNER 1536
#define D_STATE 16
#define D_CONV 4
#define DT_RANK 48
#define D_EMB 384
#define EPS 1e-5f

__device__ __forceinline__ float siluf(float x) {
    return x / (1.f + expf(-x));
}

// ---------------------------------------------------------------------------
// Embedding: hidden[t, 0:384] = emb_w[ids[t]], hidden[t, 384:768] = pos_emb_w[pos[t]]
// Also zeros residual.
// ---------------------------------------------------------------------------
__global__ void embed_kernel(const int* __restrict__ ids, const int* __restrict__ pos,
                             const float* __restrict__ emb, const float* __restrict__ pemb,
                             float* __restrict__ hidden, float* __restrict__ residual) {
    int idx = blockIdx.x * blockDim.x + threadIdx.x;
    if (idx >= BL * D_MODEL) return;
    int c = idx % D_MODEL;
    int t = idx / D_MODEL;
    float v;
    if (c < D_EMB) v = emb[(size_t)ids[t] * D_EMB + c];
    else           v = pemb[(size_t)pos[t] * (D_MODEL - D_EMB) + (c - D_EMB)];
    hidden[idx] = v;
    residual[idx] = 0.f;
}

// ---------------------------------------------------------------------------
// residual += hidden (in-place on residual); out = rmsnorm(residual) * w
// One block per token, 256 threads, 3 elems/thread (768 = 3*256).
// ---------------------------------------------------------------------------
__global__ __launch_bounds__(256) void add_rmsnorm_kernel(
    const float* __restrict__ hidden, float* __restrict__ residual,
    const float* __restrict__ w, float* __restrict__ out) {
    int row = blockIdx.x;
    const float* h = hidden + (size_t)row * D_MODEL;
    float* r = residual + (size_t)row * D_MODEL;
    float* o = out + (size_t)row * D_MODEL;

    float v[3];
    float ss = 0.f;
#pragma unroll
    for (int i = 0; i < 3; i++) {
        int c = threadIdx.x + i * 256;
        float x = h[c] + r[c];
        v[i] = x;
        r[c] = x;
        ss += x * x;
    }
    // wave (64-lane) reduce
#pragma unroll
    for (int off = 32; off > 0; off >>= 1) ss += __shfl_down(ss, off, 64);
    __shared__ float parts[4];
    __shared__ float s_scale;
    int wid = threadIdx.x >> 6;
    int lane = threadIdx.x & 63;
    if (lane == 0) parts[wid] = ss;
    __syncthreads();
    if (threadIdx.x == 0) {
        float tot = parts[0] + parts[1] + parts[2] + parts[3];
        s_scale = rsqrtf(tot / (float)D_MODEL + EPS);
    }
    __syncthreads();
    float scale = s_scale;
#pragma unroll
    for (int i = 0; i < 3; i++) {
        int c = threadIdx.x + i * 256;
        o[c] = v[i] * scale * w[c];
    }
}

// ---------------------------------------------------------------------------
// Generic GEMM: C[M,N] = A[M,K] (row-major, leading dim lda) @ B[N,K]^T
// B row-major (N rows of K). Optional bias[n], act: 0 none, 1 softplus.
// Block 64x64, BK=16, 256 threads, 4x4 micro-tile per thread.
// Requires K % 16 == 0 and M % 64 == 0 (true for all call sites).
// ---------------------------------------------------------------------------
__global__ __launch_bounds__(256) void gemm_abt_kernel(
    const float* __restrict__ A, int lda,
    const float* __restrict__ B,
    const float* __restrict__ bias,
    float* __restrict__ C,
    int M, int N, int K, int act) {
    __shared__ float As[16][65];
    __shared__ float Bs[16][65];
    int bm = blockIdx.y * 64;
    int bn = blockIdx.x * 64;
    int tid = threadIdx.x;
    int tx = tid % 16;          // -> n
    int ty = tid / 16;          // -> m
    float acc[4][4] = {};

    for (int k0 = 0; k0 < K; k0 += 16) {
#pragma unroll
        for (int i = 0; i < 4; i++) {
            int idx = tid + i * 256;
            int kk = idx % 16, mm = idx / 16;
            As[kk][mm] = A[(size_t)(bm + mm) * lda + k0 + kk];
        }
#pragma unroll
        for (int i = 0; i < 4; i++) {
            int idx = tid + i * 256;
            int kk = idx % 16, nn = idx / 16;
            int gn = bn + nn;
            Bs[kk][nn] = (gn < N) ? B[(size_t)gn * K + k0 + kk] : 0.f;
        }
        __syncthreads();
#pragma unroll
        for (int kk = 0; kk < 16; kk++) {
            float a[4], b[4];
#pragma unroll
            for (int i = 0; i < 4; i++) a[i] = As[kk][ty * 4 + i];
#pragma unroll
            for (int j = 0; j < 4; j++) b[j] = Bs[kk][tx * 4 + j];
#pragma unroll
            for (int i = 0; i < 4; i++)
#pragma unroll
                for (int j = 0; j < 4; j++)
                    acc[i][j] += a[i] * b[j];
        }
        __syncthreads();
    }
#pragma unroll
    for (int i = 0; i < 4; i++) {
        int gm = bm + ty * 4 + i;
#pragma unroll
        for (int j = 0; j < 4; j++) {
            int gn = bn + tx * 4 + j;
            if (gn < N) {
                float vv = acc[i][j];
                if (bias) vv += bias[gn];
                if (act == 1) vv = (vv > 20.f) ? vv : log1pf(expf(vv));
                C[(size_t)gm * N + gn] = vv;
            }
        }
    }
}

// ---------------------------------------------------------------------------
// Depthwise causal conv1d (k=4) + bias + SiLU.
// Input x = xz[:, :, 0:1536] with row stride 3072; output contiguous (BL,1536).
// ---------------------------------------------------------------------------
__global__ void conv_silu_kernel(const float* __restrict__ xz,
                                 const float* __restrict__ cw,
                                 const float* __restrict__ cb,
                                 float* __restrict__ out) {
    int idx = blockIdx.x * blockDim.x + threadIdx.x;
    if (idx >= BL * D_INNER) return;
    int d = idx % D_INNER;
    int t = (idx / D_INNER) % L_SZ;
    int b = idx / (D_INNER * L_SZ);
    const float* xcol = xz + (size_t)b * L_SZ * (2 * D_INNER) + d;
    float s = cb[d];
#pragma unroll
    for (int j = 0; j < D_CONV; j++) {
        int li = t - (D_CONV - 1) + j;
        if (li >= 0) s += xcol[(size_t)li * (2 * D_INNER)] * cw[d * D_CONV + j];
    }
    out[idx] = siluf(s);
}

// ---------------------------------------------------------------------------
// Selective scan, sequential over L. Grid: B * (D_INNER/256) = 12 blocks.
// Each thread owns one channel d, keeps h[16] in registers.
// Also applies the z-gate: y *= silu(z). Writes y (BL, 1536).
// ---------------------------------------------------------------------------
__global__ __launch_bounds__(256) void scan_kernel(
    const float* __restrict__ xconv, const float* __restrict__ dt,
    const float* __restrict__ xdbl, const float* __restrict__ A_log,
    const float* __restrict__ Dv, const float* __restrict__ xz,
    float* __restrict__ y) {
    int b = blockIdx.x / (D_INNER / 256);
    int dblk = blockIdx.x % (D_INNER / 256);
    int d = dblk * 256 + threadIdx.x;

    float A[D_STATE];
#pragma unroll
    for (int n = 0; n < D_STATE; n++) A[n] = -expf(A_log[(size_t)d * D_STATE + n]);
    float Dd = Dv[d];
    float h[D_STATE];
#pragma unroll
    for (int n = 0; n < D_STATE; n++) h[n] = 0.f;

    __shared__ float BC[2 * D_STATE];

    for (int t = 0; t < L_SZ; t++) {
        size_t row = (size_t)b * L_SZ + t;
        if (threadIdx.x < 2 * D_STATE)
            BC[threadIdx.x] = xdbl[row * (DT_RANK + 2 * D_STATE) + DT_RANK + threadIdx.x];
        __syncthreads();
        float dtv = dt[row * D_INNER + d];
        float xv = xconv[row * D_INNER + d];
        float acc = 0.f;
#pragma unroll
        for (int n = 0; n < D_STATE; n++) {
            h[n] = expf(dtv * A[n]) * h[n] + dtv * BC[n] * xv;
            acc += h[n] * BC[D_STATE + n];
        }
        acc += xv * Dd;
        float zv = xz[row * (2 * D_INNER) + D_INNER + d];
        y[row * D_INNER + d] = acc * siluf(zv);
        __syncthreads();
    }
}

// ---------------------------------------------------------------------------
extern "C" void kernel_launch(void* const* d_in, const int* in_sizes, int n_in,
                              void* d_out, int out_size, void* d_ws, size_t ws_size,
                              hipStream_t stream) {
    const int*   input_ids    = (const int*)d_in[0];
    const int*   position_ids = (const int*)d_in[1];
    const float* emb_w        = (const float*)d_in[2];
    const float* pos_emb_w    = (const float*)d_in[3];
    const float* norm_w       = (const float*)d_in[4];
    const float* in_proj_w    = (const float*)d_in[5];
    const float* conv_w       = (const float*)d_in[6];
    const float* conv_b       = (const float*)d_in[7];
    const float* x_proj_w     = (const float*)d_in[8];
    const float* dt_proj_w    = (const float*)d_in[9];
    const float* dt_proj_b    = (const float*)d_in[10];
    const float* A_log        = (const float*)d_in[11];
    const float* D_vec        = (const float*)d_in[12];
    const float* out_proj_w   = (const float*)d_in[13];
    const float* norm_f_w     = (const float*)d_in[14];
    float* logits = (float*)d_out;

    // Workspace layout (floats). Total ~20.6M floats = ~82.5 MB.
    float* ws = (float*)d_ws;
    float* hidden   = ws; ws += (size_t)BL * D_MODEL;
    float* residual = ws; ws += (size_t)BL * D_MODEL;
    float* hs       = ws; ws += (size_t)BL * D_MODEL;
    float* xz       = ws; ws += (size_t)BL * 2 * D_INNER;
    float* xconv    = ws; ws += (size_t)BL * D_INNER;
    float* xdbl     = ws; ws += (size_t)BL * (DT_RANK + 2 * D_STATE);
    float* dtbuf    = ws; ws += (size_t)BL * D_INNER;
    float* ybuf     = ws; ws += (size_t)BL * D_INNER;

    embed_kernel<<<(BL * D_MODEL + 255) / 256, 256, 0, stream>>>(
        input_ids, position_ids, emb_w, pos_emb_w, hidden, residual);

    for (int l = 0; l < N_LAYER; l++) {
        const float* nw  = norm_w     + (size_t)l * D_MODEL;
        const float* iw  = in_proj_w  + (size_t)l * 2 * D_INNER * D_MODEL;
        const float* cw  = conv_w     + (size_t)l * D_INNER * D_CONV;
        const float* cb  = conv_b     + (size_t)l * D_INNER;
        const float* xpw = x_proj_w   + (size_t)l * (DT_RANK + 2 * D_STATE) * D_INNER;
        const float* dtw = dt_proj_w  + (size_t)l * D_INNER * DT_RANK;
        const float* dtb = dt_proj_b  + (size_t)l * D_INNER;
        const float* al  = A_log      + (size_t)l * D_INNER * D_STATE;
        const float* dv  = D_vec      + (size_t)l * D_INNER;
        const float* ow  = out_proj_w + (size_t)l * D_MODEL * D_INNER;

        add_rmsnorm_kernel<<<BL, 256, 0, stream>>>(hidden, residual, nw, hs);

        // xz = hs @ in_w^T : M=2048, N=3072, K=768
        {
            dim3 grid((2 * D_INNER) / 64, BL / 64);
            gemm_abt_kernel<<<grid, 256, 0, stream>>>(hs, D_MODEL, iw, nullptr, xz,
                                                      BL, 2 * D_INNER, D_MODEL, 0);
        }

        conv_silu_kernel<<<(BL * D_INNER + 255) / 256, 256, 0, stream>>>(xz, cw, cb, xconv);

        // xdbl = xconv @ xp_w^T : M=2048, N=80, K=1536
        {
            dim3 grid((DT_RANK + 2 * D_STATE + 63) / 64, BL / 64);
            gemm_abt_kernel<<<grid, 256, 0, stream>>>(xconv, D_INNER, xpw, nullptr, xdbl,
                                                      BL, DT_RANK + 2 * D_STATE, D_INNER, 0);
        }

        // dt = softplus(xdbl[:, :48] @ dtw^T + dtb) : M=2048, N=1536, K=48
        {
            dim3 grid(D_INNER / 64, BL / 64);
            gemm_abt_kernel<<<grid, 256, 0, stream>>>(xdbl, DT_RANK + 2 * D_STATE, dtw, dtb,
                                                      dtbuf, BL, D_INNER, DT_RANK, 1);
        }

        scan_kernel<<<B_SZ * (D_INNER / 256), 256, 0, stream>>>(
            xconv, dtbuf, xdbl, al, dv, xz, ybuf);

        // hidden = y @ ow^T : M=2048, N=768, K=1536
        {
            dim3 grid(D_MODEL / 64, BL / 64);
            gemm_abt_kernel<<<grid, 256, 0, stream>>>(ybuf, D_INNER, ow, nullptr, hidden,
                                                      BL, D_MODEL, D_INNER, 0);
        }
    }

    add_rmsnorm_kernel<<<BL, 256, 0, stream>>>(hidden, residual, norm_f_w, hs);

    // logits = hs[:, :384] @ emb_w^T : M=2048, N=32000, K=384
    {
        dim3 grid(VOCAB / 64, BL / 64);
        gemm_abt_kernel<<<grid, 256, 0, stream>>>(hs, D_MODEL, emb_w, nullptr, logits,
                                                  BL, VOCAB, D_EMB, 0);
    }
}

// Round 2
// 5862.427 us; speedup vs baseline: 2.4425x; 2.4425x over previous
//
#include <hip/hip_runtime.h>
#include <hip/hip_bf16.h>
#include <math.h>

// Problem dims (compile-time)
#define B_SZ 2
#define L_SZ 1024
#define BL (B_SZ * L_SZ)          // 2048 tokens
#define D_MODEL 768
#define N_LAYER 6
#define VOCAB 32000
#define D_INNER 1536
#define D_STATE 16
#define D_CONV 4
#define DT_RANK 48
#define D_EMB 384
#define EPS 1e-5f

// Chunked-scan params: L = NCHUNK * CT
#define NCHUNK 64
#define CT 16
#define XD (DT_RANK + 2 * D_STATE)   // 80, xdbl row stride

__device__ __forceinline__ float siluf(float x) {
    return x / (1.f + expf(-x));
}

// ---------------------------------------------------------------------------
// Embedding: hidden[t, 0:384] = emb_w[ids[t]], hidden[t, 384:768] = pos_emb_w[pos[t]]
// Also zeros residual.
// ---------------------------------------------------------------------------
__global__ void embed_kernel(const int* __restrict__ ids, const int* __restrict__ pos,
                             const float* __restrict__ emb, const float* __restrict__ pemb,
                             float* __restrict__ hidden, float* __restrict__ residual) {
    int idx = blockIdx.x * blockDim.x + threadIdx.x;
    if (idx >= BL * D_MODEL) return;
    int c = idx % D_MODEL;
    int t = idx / D_MODEL;
    float v;
    if (c < D_EMB) v = emb[(size_t)ids[t] * D_EMB + c];
    else           v = pemb[(size_t)pos[t] * (D_MODEL - D_EMB) + (c - D_EMB)];
    hidden[idx] = v;
    residual[idx] = 0.f;
}

// ---------------------------------------------------------------------------
// residual += hidden (in-place on residual); out = rmsnorm(residual) * w
// ---------------------------------------------------------------------------
__global__ __launch_bounds__(256) void add_rmsnorm_kernel(
    const float* __restrict__ hidden, float* __restrict__ residual,
    const float* __restrict__ w, float* __restrict__ out) {
    int row = blockIdx.x;
    const float* h = hidden + (size_t)row * D_MODEL;
    float* r = residual + (size_t)row * D_MODEL;
    float* o = out + (size_t)row * D_MODEL;

    float v[3];
    float ss = 0.f;
#pragma unroll
    for (int i = 0; i < 3; i++) {
        int c = threadIdx.x + i * 256;
        float x = h[c] + r[c];
        v[i] = x;
        r[c] = x;
        ss += x * x;
    }
#pragma unroll
    for (int off = 32; off > 0; off >>= 1) ss += __shfl_down(ss, off, 64);
    __shared__ float parts[4];
    __shared__ float s_scale;
    int wid = threadIdx.x >> 6;
    int lane = threadIdx.x & 63;
    if (lane == 0) parts[wid] = ss;
    __syncthreads();
    if (threadIdx.x == 0) {
        float tot = parts[0] + parts[1] + parts[2] + parts[3];
        s_scale = rsqrtf(tot / (float)D_MODEL + EPS);
    }
    __syncthreads();
    float scale = s_scale;
#pragma unroll
    for (int i = 0; i < 3; i++) {
        int c = threadIdx.x + i * 256;
        o[c] = v[i] * scale * w[c];
    }
}

// ---------------------------------------------------------------------------
// Generic GEMM: C[M,N] = A[M,K] (row-major, lda) @ B[N,K]^T
// ---------------------------------------------------------------------------
__global__ __launch_bounds__(256) void gemm_abt_kernel(
    const float* __restrict__ A, int lda,
    const float* __restrict__ B,
    const float* __restrict__ bias,
    float* __restrict__ C,
    int M, int N, int K, int act) {
    __shared__ float As[16][65];
    __shared__ float Bs[16][65];
    int bm = blockIdx.y * 64;
    int bn = blockIdx.x * 64;
    int tid = threadIdx.x;
    int tx = tid % 16;
    int ty = tid / 16;
    float acc[4][4] = {};

    for (int k0 = 0; k0 < K; k0 += 16) {
#pragma unroll
        for (int i = 0; i < 4; i++) {
            int idx = tid + i * 256;
            int kk = idx % 16, mm = idx / 16;
            As[kk][mm] = A[(size_t)(bm + mm) * lda + k0 + kk];
        }
#pragma unroll
        for (int i = 0; i < 4; i++) {
            int idx = tid + i * 256;
            int kk = idx % 16, nn = idx / 16;
            int gn = bn + nn;
            Bs[kk][nn] = (gn < N) ? B[(size_t)gn * K + k0 + kk] : 0.f;
        }
        __syncthreads();
#pragma unroll
        for (int kk = 0; kk < 16; kk++) {
            float a[4], b[4];
#pragma unroll
            for (int i = 0; i < 4; i++) a[i] = As[kk][ty * 4 + i];
#pragma unroll
            for (int j = 0; j < 4; j++) b[j] = Bs[kk][tx * 4 + j];
#pragma unroll
            for (int i = 0; i < 4; i++)
#pragma unroll
                for (int j = 0; j < 4; j++)
                    acc[i][j] += a[i] * b[j];
        }
        __syncthreads();
    }
#pragma unroll
    for (int i = 0; i < 4; i++) {
        int gm = bm + ty * 4 + i;
#pragma unroll
        for (int j = 0; j < 4; j++) {
            int gn = bn + tx * 4 + j;
            if (gn < N) {
                float vv = acc[i][j];
                if (bias) vv += bias[gn];
                if (act == 1) vv = (vv > 20.f) ? vv : log1pf(expf(vv));
                C[(size_t)gm * N + gn] = vv;
            }
        }
    }
}

// ---------------------------------------------------------------------------
// Depthwise causal conv1d (k=4) + bias + SiLU.
// ---------------------------------------------------------------------------
__global__ void conv_silu_kernel(const float* __restrict__ xz,
                                 const float* __restrict__ cw,
                                 const float* __restrict__ cb,
                                 float* __restrict__ out) {
    int idx = blockIdx.x * blockDim.x + threadIdx.x;
    if (idx >= BL * D_INNER) return;
    int d = idx % D_INNER;
    int t = (idx / D_INNER) % L_SZ;
    int b = idx / (D_INNER * L_SZ);
    const float* xcol = xz + (size_t)b * L_SZ * (2 * D_INNER) + d;
    float s = cb[d];
#pragma unroll
    for (int j = 0; j < D_CONV; j++) {
        int li = t - (D_CONV - 1) + j;
        if (li >= 0) s += xcol[(size_t)li * (2 * D_INNER)] * cw[d * D_CONV + j];
    }
    out[idx] = siluf(s);
}

// ---------------------------------------------------------------------------
// Chunked selective scan, pass A: per-chunk decay product P and zero-seeded
// local final state S, per (b, chunk, d, n).
// Grid: (D_INNER/256, NCHUNK, B). One thread = one channel d in one chunk.
// ---------------------------------------------------------------------------
__global__ __launch_bounds__(256) void scan_passA_kernel(
    const float* __restrict__ xconv, const float* __restrict__ dt,
    const float* __restrict__ xdbl, const float* __restrict__ A_log,
    float* __restrict__ Pbuf, float* __restrict__ Sbuf) {
    int d = blockIdx.x * 256 + threadIdx.x;
    int c = blockIdx.y;
    int b = blockIdx.z;
    int t0 = c * CT;

    __shared__ float Bsh[CT][D_STATE];
    {
        int row = threadIdx.x >> 4, n = threadIdx.x & 15;   // 256 = CT*D_STATE
        Bsh[row][n] = xdbl[((size_t)(b * L_SZ + t0 + row)) * XD + DT_RANK + n];
    }
    __syncthreads();

    float A[D_STATE];
#pragma unroll
    for (int n = 0; n < D_STATE; n++) A[n] = -expf(A_log[(size_t)d * D_STATE + n]);

    float P[D_STATE], S[D_STATE];
#pragma unroll
    for (int n = 0; n < D_STATE; n++) { P[n] = 1.f; S[n] = 0.f; }

    for (int t = 0; t < CT; t++) {
        size_t row = (size_t)b * L_SZ + t0 + t;
        float dtv = dt[row * D_INNER + d];
        float xv  = xconv[row * D_INNER + d];
#pragma unroll
        for (int n = 0; n < D_STATE; n++) {
            float dA = expf(dtv * A[n]);
            P[n] *= dA;
            S[n] = dA * S[n] + dtv * Bsh[t][n] * xv;
        }
    }
    size_t base = (((size_t)b * NCHUNK + c) * D_INNER + d) * D_STATE;
#pragma unroll
    for (int n = 0; n < D_STATE; n++) { Pbuf[base + n] = P[n]; Sbuf[base + n] = S[n]; }
}

// ---------------------------------------------------------------------------
// Pass B: combine across chunks. One thread per (b,d,n) = 49152 threads.
// In-place: Pbuf[c] is overwritten with the ENTERING state of chunk c.
// ---------------------------------------------------------------------------
__global__ __launch_bounds__(256) void scan_passB_kernel(
    float* __restrict__ Pbuf, const float* __restrict__ Sbuf) {
    int idx = blockIdx.x * 256 + threadIdx.x;   // (b, d, n) flat
    int b = idx / (D_INNER * D_STATE);
    int dn = idx % (D_INNER * D_STATE);
    float H = 0.f;
    for (int c = 0; c < NCHUNK; c++) {
        size_t off = (((size_t)b * NCHUNK + c) * D_INNER * D_STATE) + dn;
        float p = Pbuf[off];
        float s = Sbuf[off];
        Pbuf[off] = H;          // entering state for chunk c
        H = p * H + s;
    }
}

// ---------------------------------------------------------------------------
// Pass C: recompute each chunk seeded with its entering state; emit gated y.
// ---------------------------------------------------------------------------
__global__ __launch_bounds__(256) void scan_passC_kernel(
    const float* __restrict__ xconv, const float* __restrict__ dt,
    const float* __restrict__ xdbl, const float* __restrict__ A_log,
    const float* __restrict__ Dv, const float* __restrict__ xz,
    const float* __restrict__ Hin,   // = Pbuf after pass B
    float* __restrict__ y) {
    int d = blockIdx.x * 256 + threadIdx.x;
    int c = blockIdx.y;
    int b = blockIdx.z;
    int t0 = c * CT;

    __shared__ float BCsh[CT][2 * D_STATE];
#pragma unroll
    for (int i = 0; i < 2; i++) {
        int idx = threadIdx.x + i * 256;       // 512 = CT * 32
        int row = idx >> 5, col = idx & 31;
        BCsh[row][col] = xdbl[((size_t)(b * L_SZ + t0 + row)) * XD + DT_RANK + col];
    }
    __syncthreads();

    float A[D_STATE];
#pragma unroll
    for (int n = 0; n < D_STATE; n++) A[n] = -expf(A_log[(size_t)d * D_STATE + n]);
    float Dd = Dv[d];

    float h[D_STATE];
    size_t hbase = (((size_t)b * NCHUNK + c) * D_INNER + d) * D_STATE;
#pragma unroll
    for (int n = 0; n < D_STATE; n++) h[n] = Hin[hbase + n];

    for (int t = 0; t < CT; t++) {
        size_t row = (size_t)b * L_SZ + t0 + t;
        float dtv = dt[row * D_INNER + d];
        float xv  = xconv[row * D_INNER + d];
        float acc = 0.f;
#pragma unroll
        for (int n = 0; n < D_STATE; n++) {
            float dA = expf(dtv * A[n]);
            h[n] = dA * h[n] + dtv * BCsh[t][n] * xv;
            acc += h[n] * BCsh[t][D_STATE + n];
        }
        acc += xv * Dd;
        float zv = xz[row * (2 * D_INNER) + D_INNER + d];
        y[row * D_INNER + d] = acc * siluf(zv);
    }
}

// ---------------------------------------------------------------------------
extern "C" void kernel_launch(void* const* d_in, const int* in_sizes, int n_in,
                              void* d_out, int out_size, void* d_ws, size_t ws_size,
                              hipStream_t stream) {
    const int*   input_ids    = (const int*)d_in[0];
    const int*   position_ids = (const int*)d_in[1];
    const float* emb_w        = (const float*)d_in[2];
    const float* pos_emb_w    = (const float*)d_in[3];
    const float* norm_w       = (const float*)d_in[4];
    const float* in_proj_w    = (const float*)d_in[5];
    const float* conv_w       = (const float*)d_in[6];
    const float* conv_b       = (const float*)d_in[7];
    const float* x_proj_w     = (const float*)d_in[8];
    const float* dt_proj_w    = (const float*)d_in[9];
    const float* dt_proj_b    = (const float*)d_in[10];
    const float* A_log        = (const float*)d_in[11];
    const float* D_vec        = (const float*)d_in[12];
    const float* out_proj_w   = (const float*)d_in[13];
    const float* norm_f_w     = (const float*)d_in[14];
    float* logits = (float*)d_out;

    // Workspace layout (floats). ~27M floats = ~108 MB.
    float* ws = (float*)d_ws;
    float* hidden   = ws; ws += (size_t)BL * D_MODEL;
    float* residual = ws; ws += (size_t)BL * D_MODEL;
    float* hs       = ws; ws += (size_t)BL * D_MODEL;
    float* xz       = ws; ws += (size_t)BL * 2 * D_INNER;
    float* xconv    = ws; ws += (size_t)BL * D_INNER;
    float* xdbl     = ws; ws += (size_t)BL * XD;
    float* dtbuf    = ws; ws += (size_t)BL * D_INNER;
    float* ybuf     = ws; ws += (size_t)BL * D_INNER;
    float* Pbuf     = ws; ws += (size_t)B_SZ * NCHUNK * D_INNER * D_STATE;
    float* Sbuf     = ws; ws += (size_t)B_SZ * NCHUNK * D_INNER * D_STATE;

    embed_kernel<<<(BL * D_MODEL + 255) / 256, 256, 0, stream>>>(
        input_ids, position_ids, emb_w, pos_emb_w, hidden, residual);

    for (int l = 0; l < N_LAYER; l++) {
        const float* nw  = norm_w     + (size_t)l * D_MODEL;
        const float* iw  = in_proj_w  + (size_t)l * 2 * D_INNER * D_MODEL;
        const float* cw  = conv_w     + (size_t)l * D_INNER * D_CONV;
        const float* cb  = conv_b     + (size_t)l * D_INNER;
        const float* xpw = x_proj_w   + (size_t)l * XD * D_INNER;
        const float* dtw = dt_proj_w  + (size_t)l * D_INNER * DT_RANK;
        const float* dtb = dt_proj_b  + (size_t)l * D_INNER;
        const float* al  = A_log      + (size_t)l * D_INNER * D_STATE;
        const float* dv  = D_vec      + (size_t)l * D_INNER;
        const float* ow  = out_proj_w + (size_t)l * D_MODEL * D_INNER;

        add_rmsnorm_kernel<<<BL, 256, 0, stream>>>(hidden, residual, nw, hs);

        {   // xz = hs @ in_w^T : M=2048, N=3072, K=768
            dim3 grid((2 * D_INNER) / 64, BL / 64);
            gemm_abt_kernel<<<grid, 256, 0, stream>>>(hs, D_MODEL, iw, nullptr, xz,
                                                      BL, 2 * D_INNER, D_MODEL, 0);
        }

        conv_silu_kernel<<<(BL * D_INNER + 255) / 256, 256, 0, stream>>>(xz, cw, cb, xconv);

        {   // xdbl = xconv @ xp_w^T : M=2048, N=80, K=1536
            dim3 grid((XD + 63) / 64, BL / 64);
            gemm_abt_kernel<<<grid, 256, 0, stream>>>(xconv, D_INNER, xpw, nullptr, xdbl,
                                                      BL, XD, D_INNER, 0);
        }

        {   // dt = softplus(xdbl[:, :48] @ dtw^T + dtb) : M=2048, N=1536, K=48
            dim3 grid(D_INNER / 64, BL / 64);
            gemm_abt_kernel<<<grid, 256, 0, stream>>>(xdbl, XD, dtw, dtb,
                                                      dtbuf, BL, D_INNER, DT_RANK, 1);
        }

        {   // chunked selective scan
            dim3 gA(D_INNER / 256, NCHUNK, B_SZ);
            scan_passA_kernel<<<gA, 256, 0, stream>>>(xconv, dtbuf, xdbl, al, Pbuf, Sbuf);
            scan_passB_kernel<<<(B_SZ * D_INNER * D_STATE) / 256, 256, 0, stream>>>(Pbuf, Sbuf);
            scan_passC_kernel<<<gA, 256, 0, stream>>>(xconv, dtbuf, xdbl, al, dv, xz,
                                                      Pbuf, ybuf);
        }

        {   // hidden = y @ ow^T : M=2048, N=768, K=1536
            dim3 grid(D_MODEL / 64, BL / 64);
            gemm_abt_kernel<<<grid, 256, 0, stream>>>(ybuf, D_INNER, ow, nullptr, hidden,
                                                      BL, D_MODEL, D_INNER, 0);
        }
    }

    add_rmsnorm_kernel<<<BL, 256, 0, stream>>>(hidden, residual, norm_f_w, hs);

    {   // logits = hs[:, :384] @ emb_w^T : M=2048, N=32000, K=384
        dim3 grid(VOCAB / 64, BL / 64);
        gemm_abt_kernel<<<grid, 256, 0, stream>>>(hs, D_MODEL, emb_w, nullptr, logits,
                                                  BL, VOCAB, D_EMB, 0);
    }
}